// Round 5
// baseline (140.851 us; speedup 1.0000x reference)
//
#include <hip/hip_runtime.h>
#include <math.h>

constexpr int BS = 16;
constexpr int G  = 512;
constexpr int S  = 20;
constexpr int Q  = 256;
constexpr int P  = G * S;                 // 10240
constexpr int P1_TASKS = BS * (P / 256);  // 640: own 256 pred / stage 256 gt
constexpr int P2_TASKS = BS * (P / 64);   // 2560: stage 64 pred / own 256 gt
constexpr int NBLOCKS  = P1_TASKS + P2_TASKS;  // 3200
constexpr float THRESHOLD = 0.01f;
constexpr float FARV = 1e15f;             // masked-out pred sentinel (d2 ~ 3e30, finite)
constexpr float FINF = 3.4e38f;

// ws word offsets
constexpr int WQM = 0;                    // [BS*Q]  qmin d2 bits; memset 0xAA (= +inf for unsigned min)
constexpr int WC1 = WQM + BS * Q;         // [640]   cd1 partial per phase-1 task (pure write)
constexpr int WB  = WC1 + P1_TASKS;       // [32]    bce partials (pure write)
constexpr int WCN = WB + 32;              // [32]    masked-cell-count partials (pure write)
constexpr int WCT = WCN + 32;             // [1]     block counter; memset 0

__global__ __launch_bounds__(64) void loss_kernel(
        const float* __restrict__ pred,     // [BS,P,3]
        const float* __restrict__ probs,    // [BS,G]
        const float* __restrict__ gt,       // [BS,Q,3]
        const float* __restrict__ target,   // [BS,G]
        float* __restrict__ ws,
        float* __restrict__ out) {
    const int bid = blockIdx.x;
    const int l   = threadIdx.x;            // 0..63
    __shared__ float4 sx4[64], sy4[64], sz4[64];
    unsigned* wsu = (unsigned*)ws;

    if (bid < P1_TASKS) {
        // ---- phase 1 (cd1): own 4 pred points/lane, stage all 256 gt ----
        const int b   = bid / 40;
        const int grp = bid % 40;

        // stage gt SoA: lane l handles gt points 4l..4l+3 (3 coalesced float4 loads)
        const float4* gsrc = (const float4*)(gt + (size_t)b * Q * 3);
        float4 a0 = gsrc[3 * l], a1 = gsrc[3 * l + 1], a2 = gsrc[3 * l + 2];
        sx4[l] = make_float4(a0.x, a0.w, a1.z, a2.y);
        sy4[l] = make_float4(a0.y, a1.x, a1.w, a2.z);
        sz4[l] = make_float4(a0.z, a1.y, a2.x, a2.w);

        // own pred points grp*256 + 4l .. +3 (3 coalesced float4 loads)
        const float4* psrc = (const float4*)(pred + ((size_t)b * P + grp * 256) * 3);
        float4 c0 = psrc[3 * l], c1 = psrc[3 * l + 1], c2 = psrc[3 * l + 2];
        float oxr[4] = {c0.x, c0.w, c1.z, c2.y};
        float oyr[4] = {c0.y, c1.x, c1.w, c2.z};
        float ozr[4] = {c0.z, c1.y, c2.x, c2.w};
        const int p0 = grp * 256 + 4 * l;
        float om[4];
        #pragma unroll
        for (int j = 0; j < 4; ++j)
            om[j] = (probs[b * G + (p0 + j) / S] > THRESHOLD) ? 1.0f : 0.0f;
        __syncthreads();

        float acc[4][4];
        #pragma unroll
        for (int j = 0; j < 4; ++j)
            #pragma unroll
            for (int k = 0; k < 4; ++k) acc[j][k] = FINF;

        #pragma unroll 4
        for (int g = 0; g < 64; ++g) {
            float4 X = sx4[g], Y = sy4[g], Z = sz4[g];
            float gx[4] = {X.x, X.y, X.z, X.w};
            float gy[4] = {Y.x, Y.y, Y.z, Y.w};
            float gz[4] = {Z.x, Z.y, Z.z, Z.w};
            #pragma unroll
            for (int k = 0; k < 4; ++k)
                #pragma unroll
                for (int j = 0; j < 4; ++j) {
                    float dx = oxr[j] - gx[k];
                    float dy = oyr[j] - gy[k];
                    float dz = ozr[j] - gz[k];
                    float d  = dx * dx + dy * dy + dz * dz;
                    acc[j][k] = fminf(acc[j][k], d);
                }
        }
        float contrib = 0.0f;
        #pragma unroll
        for (int j = 0; j < 4; ++j) {
            float mn = fminf(fminf(acc[j][0], acc[j][1]), fminf(acc[j][2], acc[j][3]));
            contrib += om[j] * sqrtf(mn);
        }
        for (int off = 32; off; off >>= 1) contrib += __shfl_down(contrib, off);
        if (l == 0) ws[WC1 + bid] = contrib;

        // ---- BCE + cell count folded into blocks 0..31 (4 cells/lane) ----
        if (bid < 32) {
            float term = 0.0f, cells = 0.0f;
            #pragma unroll
            for (int j = 0; j < 4; ++j) {
                int cell = bid * 256 + 4 * l + j;
                float pv = probs[cell];
                float tv = target[cell];
                term += -(tv * fmaxf(logf(pv), -100.0f) +
                          (1.0f - tv) * fmaxf(log1pf(-pv), -100.0f));
                cells += (pv > THRESHOLD) ? 1.0f : 0.0f;
            }
            for (int off = 32; off; off >>= 1) {
                term  += __shfl_down(term, off);
                cells += __shfl_down(cells, off);
            }
            if (l == 0) { ws[WB + bid] = term; ws[WCN + bid] = cells; }
        }
    } else {
        // ---- phase 2 (cd2): stage 64 pred (mask-folded), own all 256 gt (4/lane) ----
        const int id  = bid - P1_TASKS;
        const int b   = id / 160;
        const int grp = id % 160;

        int p = grp * 64 + l;
        const float* pp = pred + ((size_t)b * P + p) * 3;
        bool m = probs[b * G + p / S] > THRESHOLD;
        float* sxf = (float*)sx4; float* syf = (float*)sy4; float* szf = (float*)sz4;
        sxf[l] = m ? pp[0] : FARV;
        syf[l] = m ? pp[1] : FARV;
        szf[l] = m ? pp[2] : FARV;

        float ogx[4], ogy[4], ogz[4];
        #pragma unroll
        for (int j = 0; j < 4; ++j) {
            const float* gq = gt + ((size_t)b * Q + l + 64 * j) * 3;
            ogx[j] = gq[0]; ogy[j] = gq[1]; ogz[j] = gq[2];
        }
        __syncthreads();

        float acc[4][4];
        #pragma unroll
        for (int j = 0; j < 4; ++j)
            #pragma unroll
            for (int k = 0; k < 4; ++k) acc[j][k] = FINF;

        #pragma unroll
        for (int g = 0; g < 16; ++g) {
            float4 X = sx4[g], Y = sy4[g], Z = sz4[g];
            float gx[4] = {X.x, X.y, X.z, X.w};
            float gy[4] = {Y.x, Y.y, Y.z, Y.w};
            float gz[4] = {Z.x, Z.y, Z.z, Z.w};
            #pragma unroll
            for (int k = 0; k < 4; ++k)
                #pragma unroll
                for (int j = 0; j < 4; ++j) {
                    float dx = ogx[j] - gx[k];
                    float dy = ogy[j] - gy[k];
                    float dz = ogz[j] - gz[k];
                    float d  = dx * dx + dy * dy + dz * dz;
                    acc[j][k] = fminf(acc[j][k], d);
                }
        }
        #pragma unroll
        for (int j = 0; j < 4; ++j) {
            float mn = fminf(fminf(acc[j][0], acc[j][1]), fminf(acc[j][2], acc[j][3]));
            atomicMin(&wsu[WQM + b * Q + l + 64 * j], __float_as_uint(mn));  // d2 >= 0: uint min == float min
        }
    }

    // ---- completion counter; last block finalizes ----
    __threadfence();
    unsigned old = 0;
    if (l == 0) old = atomicAdd(&wsu[WCT], 1u);
    old = (unsigned)__shfl((int)old, 0);
    if (old == (unsigned)(NBLOCKS - 1)) {
        __threadfence();
        float accv = 0.0f;   // meaningful on lane 0
        for (int b = 0; b < BS; ++b) {
            float s2 = 0.0f;
            #pragma unroll
            for (int j = 0; j < 4; ++j)
                s2 += sqrtf(__uint_as_float(wsu[WQM + b * Q + l + 64 * j]));
            for (int off = 32; off; off >>= 1) s2 += __shfl_down(s2, off);

            float s1 = (l < 40) ? ws[WC1 + b * 40 + l] : 0.0f;
            for (int off = 32; off; off >>= 1) s1 += __shfl_down(s1, off);

            if (l == 0) {
                float cnt = (ws[WCN + 2 * b] + ws[WCN + 2 * b + 1]) * (float)S;
                float cd1 = s1 / fmaxf(cnt, 1.0f);
                float cd2 = s2 / (float)Q;
                accv += (cnt > 0.0f) ? fmaxf(cd1, cd2) : 0.0f;
            }
        }
        float bb = (l < 32) ? ws[WB + l] : 0.0f;
        for (int off = 32; off; off >>= 1) bb += __shfl_down(bb, off);
        if (l == 0) out[0] = bb / (float)(BS * G) + accv / (float)BS;
    }
}

extern "C" void kernel_launch(void* const* d_in, const int* in_sizes, int n_in,
                              void* d_out, int out_size, void* d_ws, size_t ws_size,
                              hipStream_t stream) {
    const float* diff_pred   = (const float*)d_in[0];
    const float* probs_pred  = (const float*)d_in[1];
    const float* diff_gt     = (const float*)d_in[2];
    const float* prob_target = (const float*)d_in[3];
    float* out = (float*)d_out;
    float* ws  = (float*)d_ws;

    // self-owned init (graph-capturable): qmin -> 0xAAAAAAAA (unsigned +inf), counter -> 0
    hipMemsetAsync((char*)ws + WQM * 4, 0xAA, (size_t)BS * Q * 4, stream);
    hipMemsetAsync((char*)ws + WCT * 4, 0x00, 4, stream);

    loss_kernel<<<NBLOCKS, 64, 0, stream>>>(
        diff_pred, probs_pred, diff_gt, prob_target, ws, out);
}

// Round 6
// 118.403 us; speedup vs baseline: 1.1896x; 1.1896x over previous
//
#include <hip/hip_runtime.h>
#include <math.h>

constexpr int BS = 16;
constexpr int G  = 512;
constexpr int S  = 20;
constexpr int Q  = 256;
constexpr int P  = G * S;                 // 10240
constexpr int NCHUNK = P / 256;           // 40 slices of 256 pred points
constexpr int NTASK1 = BS * NCHUNK;       // 640 phase-1 wave-tasks (cd1)
constexpr int NTASK2 = BS * NCHUNK;       // 640 phase-2 wave-tasks (cd2)
constexpr int NTASKS = NTASK1 + NTASK2;   // 1280 waves = 320 blocks x 4
constexpr float THRESHOLD = 0.01f;
constexpr float FARV = 1e15f;             // masked-out pred sentinel (d2 ~ 3e30, finite)
constexpr float FINF = 3.4e38f;

// ws float offsets — ALL pure writes, read only by finalize (no init needed)
constexpr int WQ  = 0;                    // qpart[BS][NCHUNK][Q] d2 = 163840
constexpr int WC1 = WQ + BS * NCHUNK * Q; // cd1 partial per phase-1 task [640]
constexpr int WB  = WC1 + NTASK1;         // bce partials [32]
constexpr int WCN = WB + 32;              // masked-cell-count partials [32]

// 320 blocks x 256 threads; each wave is an independent task, no block barriers.
__global__ __launch_bounds__(256) void chamfer_kernel(
        const float* __restrict__ pred,     // [BS,P,3]
        const float* __restrict__ probs,    // [BS,G]
        const float* __restrict__ gt,       // [BS,Q,3]
        const float* __restrict__ target,   // [BS,G]
        float* __restrict__ ws) {
    const int wid  = threadIdx.x >> 6;       // wave 0..3 (private LDS region)
    const int l    = threadIdx.x & 63;
    const int task = blockIdx.x * 4 + wid;   // 0..1279

    __shared__ float4 sx4[4][64], sy4[4][64], sz4[4][64];

    const int phase1 = (task < NTASK1);
    const int id  = phase1 ? task : task - NTASK1;
    const int b   = id / NCHUNK;
    const int grp = id % NCHUNK;

    // Both phases: lane owns 4 points (float4-swizzled coalesced load),
    // wave stages 256 opposing points SoA in its private LDS region.
    float oxr[4], oyr[4], ozr[4];
    float om[4];

    if (phase1) {
        // stage gt; own 4 pred points (+ mask multiplier)
        const float4* gsrc = (const float4*)(gt + (size_t)b * Q * 3);
        float4 a0 = gsrc[3 * l], a1 = gsrc[3 * l + 1], a2 = gsrc[3 * l + 2];
        sx4[wid][l] = make_float4(a0.x, a0.w, a1.z, a2.y);
        sy4[wid][l] = make_float4(a0.y, a1.x, a1.w, a2.z);
        sz4[wid][l] = make_float4(a0.z, a1.y, a2.x, a2.w);

        const float4* psrc = (const float4*)(pred + ((size_t)b * P + grp * 256) * 3);
        float4 c0 = psrc[3 * l], c1 = psrc[3 * l + 1], c2 = psrc[3 * l + 2];
        oxr[0] = c0.x; oxr[1] = c0.w; oxr[2] = c1.z; oxr[3] = c2.y;
        oyr[0] = c0.y; oyr[1] = c1.x; oyr[2] = c1.w; oyr[3] = c2.z;
        ozr[0] = c0.z; ozr[1] = c1.y; ozr[2] = c2.x; ozr[3] = c2.w;
        const int p0 = grp * 256 + 4 * l;
        #pragma unroll
        for (int j = 0; j < 4; ++j)
            om[j] = (probs[b * G + (p0 + j) / S] > THRESHOLD) ? 1.0f : 0.0f;
    } else {
        // stage pred slice (mask-folded to FARV); own 4 gt points
        const float4* psrc = (const float4*)(pred + ((size_t)b * P + grp * 256) * 3);
        float4 c0 = psrc[3 * l], c1 = psrc[3 * l + 1], c2 = psrc[3 * l + 2];
        const int p0 = grp * 256 + 4 * l;
        bool m0 = probs[b * G + (p0 + 0) / S] > THRESHOLD;
        bool m1 = probs[b * G + (p0 + 1) / S] > THRESHOLD;
        bool m2 = probs[b * G + (p0 + 2) / S] > THRESHOLD;
        bool m3 = probs[b * G + (p0 + 3) / S] > THRESHOLD;
        sx4[wid][l] = make_float4(m0 ? c0.x : FARV, m1 ? c0.w : FARV,
                                  m2 ? c1.z : FARV, m3 ? c2.y : FARV);
        sy4[wid][l] = make_float4(m0 ? c0.y : FARV, m1 ? c1.x : FARV,
                                  m2 ? c1.w : FARV, m3 ? c2.z : FARV);
        sz4[wid][l] = make_float4(m0 ? c0.z : FARV, m1 ? c1.y : FARV,
                                  m2 ? c2.x : FARV, m3 ? c2.w : FARV);

        const float4* gsrc = (const float4*)(gt + (size_t)b * Q * 3);
        float4 a0 = gsrc[3 * l], a1 = gsrc[3 * l + 1], a2 = gsrc[3 * l + 2];
        oxr[0] = a0.x; oxr[1] = a0.w; oxr[2] = a1.z; oxr[3] = a2.y;
        oyr[0] = a0.y; oyr[1] = a1.x; oyr[2] = a1.w; oyr[3] = a2.z;
        ozr[0] = a0.z; ozr[1] = a1.y; ozr[2] = a2.x; ozr[3] = a2.w;
    }
    // wave-private LDS region: same-wave write->read, compiler inserts lgkmcnt wait

    float acc[4][4];
    #pragma unroll
    for (int j = 0; j < 4; ++j)
        #pragma unroll
        for (int k = 0; k < 4; ++k) acc[j][k] = FINF;

    #pragma unroll 4
    for (int g = 0; g < 64; ++g) {
        float4 X = sx4[wid][g], Y = sy4[wid][g], Z = sz4[wid][g];  // uniform broadcast
        float gx[4] = {X.x, X.y, X.z, X.w};
        float gy[4] = {Y.x, Y.y, Y.z, Y.w};
        float gz[4] = {Z.x, Z.y, Z.z, Z.w};
        #pragma unroll
        for (int k = 0; k < 4; ++k)
            #pragma unroll
            for (int j = 0; j < 4; ++j) {
                float dx = oxr[j] - gx[k];
                float dy = oyr[j] - gy[k];
                float dz = ozr[j] - gz[k];
                float d  = dx * dx + dy * dy + dz * dz;
                acc[j][k] = fminf(acc[j][k], d);
            }
    }
    float mn[4];
    #pragma unroll
    for (int j = 0; j < 4; ++j)
        mn[j] = fminf(fminf(acc[j][0], acc[j][1]), fminf(acc[j][2], acc[j][3]));

    if (phase1) {
        float contrib = om[0] * sqrtf(mn[0]) + om[1] * sqrtf(mn[1]) +
                        om[2] * sqrtf(mn[2]) + om[3] * sqrtf(mn[3]);
        #pragma unroll
        for (int off = 32; off; off >>= 1) contrib += __shfl_down(contrib, off);
        if (l == 0) ws[WC1 + id] = contrib;

        // BCE + mask-cell count folded into tasks 0..31 (256 cells each)
        if (task < 32) {
            float term = 0.0f, cells = 0.0f;
            #pragma unroll
            for (int j = 0; j < 4; ++j) {
                int cell = task * 256 + 4 * l + j;
                float pv = probs[cell];
                float tv = target[cell];
                term += -(tv * fmaxf(logf(pv), -100.0f) +
                          (1.0f - tv) * fmaxf(log1pf(-pv), -100.0f));
                cells += (pv > THRESHOLD) ? 1.0f : 0.0f;
            }
            #pragma unroll
            for (int off = 32; off; off >>= 1) {
                term  += __shfl_down(term, off);
                cells += __shfl_down(cells, off);
            }
            if (l == 0) { ws[WB + task] = term; ws[WCN + task] = cells; }
        }
    } else {
        // pure coalesced float4 store of this slice's per-gt min d2
        float4 v = make_float4(mn[0], mn[1], mn[2], mn[3]);
        *(float4*)(ws + WQ + ((size_t)b * NCHUNK + grp) * Q + 4 * l) = v;
    }
}

// 1 block x 1024 threads.
__global__ __launch_bounds__(1024) void finalize_kernel(
        const float* __restrict__ ws, float* __restrict__ out) {
    int tid = threadIdx.x;
    __shared__ float sums[16][4];
    __shared__ float scd1[16], scnt[16], sbce[1];
    if (tid < 16) { scd1[tid] = 0.0f; scnt[tid] = 0.0f; }
    if (tid == 0) sbce[0] = 0.0f;
    __syncthreads();

    // qpart: min d2 over 40 slices per (b,q), sqrt, per-batch sum
    #pragma unroll
    for (int k = 0; k < 4; ++k) {
        int id = k * 1024 + tid;          // (b,q), b wave-uniform
        int b = id >> 8, q = id & 255;
        const float* qp = ws + WQ + (size_t)b * NCHUNK * Q + q;
        float mnv = FINF;
        #pragma unroll 8
        for (int c = 0; c < NCHUNK; ++c) mnv = fminf(mnv, qp[c * Q]);
        float s = sqrtf(mnv);
        #pragma unroll
        for (int off = 32; off; off >>= 1) s += __shfl_down(s, off);
        int w = tid >> 6;
        if ((tid & 63) == 0) sums[b][w & 3] = s;
    }
    if (tid < NTASK1) atomicAdd(&scd1[tid / NCHUNK], ws[WC1 + tid]);
    if (tid < 32) {
        atomicAdd(&sbce[0], ws[WB + tid]);
        atomicAdd(&scnt[tid >> 1], ws[WCN + tid]);
    }
    __syncthreads();

    if (tid == 0) {
        float acc = 0.0f;
        #pragma unroll
        for (int b = 0; b < 16; ++b) {
            float cd2 = (sums[b][0] + sums[b][1] + sums[b][2] + sums[b][3]) / (float)Q;
            float cnt = scnt[b] * (float)S;
            float cd1 = scd1[b] / fmaxf(cnt, 1.0f);
            acc += (cnt > 0.0f) ? fmaxf(cd1, cd2) : 0.0f;
        }
        out[0] = sbce[0] / (float)(BS * G) + acc / (float)BS;
    }
}

extern "C" void kernel_launch(void* const* d_in, const int* in_sizes, int n_in,
                              void* d_out, int out_size, void* d_ws, size_t ws_size,
                              hipStream_t stream) {
    const float* diff_pred   = (const float*)d_in[0];
    const float* probs_pred  = (const float*)d_in[1];
    const float* diff_gt     = (const float*)d_in[2];
    const float* prob_target = (const float*)d_in[3];
    float* out = (float*)d_out;
    float* ws  = (float*)d_ws;

    chamfer_kernel<<<NTASKS / 4, 256, 0, stream>>>(
        diff_pred, probs_pred, diff_gt, prob_target, ws);
    finalize_kernel<<<1, 1024, 0, stream>>>(ws, out);
}

// Round 7
// 86.552 us; speedup vs baseline: 1.6274x; 1.3680x over previous
//
#include <hip/hip_runtime.h>
#include <math.h>

constexpr int BS = 16;
constexpr int G  = 512;
constexpr int S  = 20;
constexpr int Q  = 256;
constexpr int P  = G * S;                 // 10240
constexpr int NCHUNK = P / 256;           // 40 slices of 256 pred points
constexpr int NTASK1 = BS * NCHUNK;       // 640 phase-1 wave-tasks (cd1)
constexpr int NTASK2 = BS * NCHUNK;       // 640 phase-2 wave-tasks (cd2)
constexpr int NTASKS = NTASK1 + NTASK2;   // 1280 waves = 320 blocks x 4
constexpr float THRESHOLD = 0.01f;
constexpr float FARV = 1e15f;             // masked-out pred sentinel (d2 ~ 3e30, finite)
constexpr float FINF = 3.4e38f;

// ws float offsets — ALL pure writes, read only by finalize (no init needed)
constexpr int WQ  = 0;                    // qpart[BS][NCHUNK][Q] d2 = 163840
constexpr int WC1 = WQ + BS * NCHUNK * Q; // cd1 partial per phase-1 task [640]
constexpr int WB  = WC1 + NTASK1;         // bce partials [32]
constexpr int WCN = WB + 32;              // masked-cell-count partials [32]

// 320 blocks x 256 threads; each wave is an independent task, no block barriers.
__global__ __launch_bounds__(256) void chamfer_kernel(
        const float* __restrict__ pred,     // [BS,P,3]
        const float* __restrict__ probs,    // [BS,G]
        const float* __restrict__ gt,       // [BS,Q,3]
        const float* __restrict__ target,   // [BS,G]
        float* __restrict__ ws) {
    const int wid  = threadIdx.x >> 6;       // wave 0..3 (private LDS region)
    const int l    = threadIdx.x & 63;
    const int task = blockIdx.x * 4 + wid;   // 0..1279

    __shared__ float4 sx4[4][64], sy4[4][64], sz4[4][64];

    const int phase1 = (task < NTASK1);
    const int id  = phase1 ? task : task - NTASK1;
    const int b   = id / NCHUNK;
    const int grp = id % NCHUNK;

    float oxr[4], oyr[4], ozr[4];
    float om[4];

    if (phase1) {
        // stage gt; own 4 pred points (+ mask multiplier)
        const float4* gsrc = (const float4*)(gt + (size_t)b * Q * 3);
        float4 a0 = gsrc[3 * l], a1 = gsrc[3 * l + 1], a2 = gsrc[3 * l + 2];
        sx4[wid][l] = make_float4(a0.x, a0.w, a1.z, a2.y);
        sy4[wid][l] = make_float4(a0.y, a1.x, a1.w, a2.z);
        sz4[wid][l] = make_float4(a0.z, a1.y, a2.x, a2.w);

        const float4* psrc = (const float4*)(pred + ((size_t)b * P + grp * 256) * 3);
        float4 c0 = psrc[3 * l], c1 = psrc[3 * l + 1], c2 = psrc[3 * l + 2];
        oxr[0] = c0.x; oxr[1] = c0.w; oxr[2] = c1.z; oxr[3] = c2.y;
        oyr[0] = c0.y; oyr[1] = c1.x; oyr[2] = c1.w; oyr[3] = c2.z;
        ozr[0] = c0.z; ozr[1] = c1.y; ozr[2] = c2.x; ozr[3] = c2.w;
        const int p0 = grp * 256 + 4 * l;
        #pragma unroll
        for (int j = 0; j < 4; ++j)
            om[j] = (probs[b * G + (p0 + j) / S] > THRESHOLD) ? 1.0f : 0.0f;
    } else {
        // stage pred slice (mask-folded to FARV); own 4 gt points
        const float4* psrc = (const float4*)(pred + ((size_t)b * P + grp * 256) * 3);
        float4 c0 = psrc[3 * l], c1 = psrc[3 * l + 1], c2 = psrc[3 * l + 2];
        const int p0 = grp * 256 + 4 * l;
        bool m0 = probs[b * G + (p0 + 0) / S] > THRESHOLD;
        bool m1 = probs[b * G + (p0 + 1) / S] > THRESHOLD;
        bool m2 = probs[b * G + (p0 + 2) / S] > THRESHOLD;
        bool m3 = probs[b * G + (p0 + 3) / S] > THRESHOLD;
        sx4[wid][l] = make_float4(m0 ? c0.x : FARV, m1 ? c0.w : FARV,
                                  m2 ? c1.z : FARV, m3 ? c2.y : FARV);
        sy4[wid][l] = make_float4(m0 ? c0.y : FARV, m1 ? c1.x : FARV,
                                  m2 ? c1.w : FARV, m3 ? c2.z : FARV);
        sz4[wid][l] = make_float4(m0 ? c0.z : FARV, m1 ? c1.y : FARV,
                                  m2 ? c2.x : FARV, m3 ? c2.w : FARV);

        const float4* gsrc = (const float4*)(gt + (size_t)b * Q * 3);
        float4 a0 = gsrc[3 * l], a1 = gsrc[3 * l + 1], a2 = gsrc[3 * l + 2];
        oxr[0] = a0.x; oxr[1] = a0.w; oxr[2] = a1.z; oxr[3] = a2.y;
        oyr[0] = a0.y; oyr[1] = a1.x; oyr[2] = a1.w; oyr[3] = a2.z;
        ozr[0] = a0.z; ozr[1] = a1.y; ozr[2] = a2.x; ozr[3] = a2.w;
    }
    // wave-private LDS region: same-wave write->read, compiler inserts lgkmcnt wait

    float acc[4][4];
    #pragma unroll
    for (int j = 0; j < 4; ++j)
        #pragma unroll
        for (int k = 0; k < 4; ++k) acc[j][k] = FINF;

    #pragma unroll 4
    for (int g = 0; g < 64; ++g) {
        float4 X = sx4[wid][g], Y = sy4[wid][g], Z = sz4[wid][g];  // uniform broadcast
        float gx[4] = {X.x, X.y, X.z, X.w};
        float gy[4] = {Y.x, Y.y, Y.z, Y.w};
        float gz[4] = {Z.x, Z.y, Z.z, Z.w};
        #pragma unroll
        for (int k = 0; k < 4; ++k)
            #pragma unroll
            for (int j = 0; j < 4; ++j) {
                float dx = oxr[j] - gx[k];
                float dy = oyr[j] - gy[k];
                float dz = ozr[j] - gz[k];
                float d  = dx * dx + dy * dy + dz * dz;
                acc[j][k] = fminf(acc[j][k], d);
            }
    }
    float mn[4];
    #pragma unroll
    for (int j = 0; j < 4; ++j)
        mn[j] = fminf(fminf(acc[j][0], acc[j][1]), fminf(acc[j][2], acc[j][3]));

    if (phase1) {
        float contrib = om[0] * sqrtf(mn[0]) + om[1] * sqrtf(mn[1]) +
                        om[2] * sqrtf(mn[2]) + om[3] * sqrtf(mn[3]);
        #pragma unroll
        for (int off = 32; off; off >>= 1) contrib += __shfl_down(contrib, off);
        if (l == 0) ws[WC1 + id] = contrib;

        // BCE + mask-cell count folded into tasks 0..31 (256 cells each)
        if (task < 32) {
            float term = 0.0f, cells = 0.0f;
            #pragma unroll
            for (int j = 0; j < 4; ++j) {
                int cell = task * 256 + 4 * l + j;
                float pv = probs[cell];
                float tv = target[cell];
                term += -(tv * fmaxf(logf(pv), -100.0f) +
                          (1.0f - tv) * fmaxf(log1pf(-pv), -100.0f));
                cells += (pv > THRESHOLD) ? 1.0f : 0.0f;
            }
            #pragma unroll
            for (int off = 32; off; off >>= 1) {
                term  += __shfl_down(term, off);
                cells += __shfl_down(cells, off);
            }
            if (l == 0) { ws[WB + task] = term; ws[WCN + task] = cells; }
        }
    } else {
        // pure coalesced float4 store of this slice's per-gt min d2
        float4 v = make_float4(mn[0], mn[1], mn[2], mn[3]);
        *(float4*)(ws + WQ + ((size_t)b * NCHUNK + grp) * Q + 4 * l) = v;
    }
}

// grid = 16 blocks x 256 threads; block b handles batch b entirely.
// Thread q: min over 40 chunk partials (coalesced, independent loads), sqrt, sum.
__global__ __launch_bounds__(256) void finalize_kernel(
        const float* __restrict__ ws, float* __restrict__ out) {
    const int b = blockIdx.x;
    const int t = threadIdx.x;              // == q
    __shared__ float sred[4];

    const float* qp = ws + WQ + (size_t)b * NCHUNK * Q + t;
    float mnv = FINF;
    #pragma unroll
    for (int c = 0; c < NCHUNK; ++c) mnv = fminf(mnv, qp[c * Q]);
    float s2 = sqrtf(mnv);

    // cd1 partials (threads 0..39) folded into the same reduction lanes
    float s1 = (t < NTASK1 / BS) ? ws[WC1 + b * NCHUNK + t] : 0.0f;

    #pragma unroll
    for (int off = 32; off; off >>= 1) {
        s2 += __shfl_down(s2, off);
        s1 += __shfl_down(s1, off);
    }
    if ((t & 63) == 0) sred[t >> 6] = s2;   // s1 lives entirely in wave 0
    __syncthreads();

    if (t == 0) {
        float sum2 = sred[0] + sred[1] + sred[2] + sred[3];
        float cnt  = (ws[WCN + 2 * b] + ws[WCN + 2 * b + 1]) * (float)S;
        float cd1  = s1 / fmaxf(cnt, 1.0f);
        float cd2  = sum2 / (float)Q;
        float cdb  = (cnt > 0.0f) ? fmaxf(cd1, cd2) : 0.0f;
        atomicAdd(out, cdb / (float)BS);
    }
    // block 0, wave 1: BCE sum (32 partials)
    if (b == 0 && t >= 64 && t < 128) {
        int l = t - 64;
        float bb = (l < 32) ? ws[WB + l] : 0.0f;
        #pragma unroll
        for (int off = 32; off; off >>= 1) bb += __shfl_down(bb, off);
        if (l == 0) atomicAdd(out, bb / (float)(BS * G));
    }
}

extern "C" void kernel_launch(void* const* d_in, const int* in_sizes, int n_in,
                              void* d_out, int out_size, void* d_ws, size_t ws_size,
                              hipStream_t stream) {
    const float* diff_pred   = (const float*)d_in[0];
    const float* probs_pred  = (const float*)d_in[1];
    const float* diff_gt     = (const float*)d_in[2];
    const float* prob_target = (const float*)d_in[3];
    float* out = (float*)d_out;
    float* ws  = (float*)d_ws;

    hipMemsetAsync(out, 0, sizeof(float), stream);   // out accumulated via atomicAdd
    chamfer_kernel<<<NTASKS / 4, 256, 0, stream>>>(
        diff_pred, probs_pred, diff_gt, prob_target, ws);
    finalize_kernel<<<BS, 256, 0, stream>>>(ws, out);
}

// Round 8
// 80.122 us; speedup vs baseline: 1.7580x; 1.0803x over previous
//
#include <hip/hip_runtime.h>
#include <math.h>

constexpr int BS = 16;
constexpr int G  = 512;
constexpr int S  = 20;
constexpr int Q  = 256;
constexpr int P  = G * S;                 // 10240
constexpr int NSLICE = 32;                // slices per batch per phase
constexpr int SLICE  = P / NSLICE;        // 320 pred points per slice (= 16 cells)
constexpr int NTASK1 = BS * NSLICE;       // 512 phase-1 wave-tasks (cd1)
constexpr int NTASKS = 2 * NTASK1;        // 1024 waves = 256 blocks x 4 = 1 wave/SIMD
constexpr float THRESHOLD = 0.01f;
constexpr float FARV = 1e15f;             // masked-out pred sentinel (d2 ~ 3e30, finite)
constexpr float FINF = 3.4e38f;

// ws float offsets — ALL pure writes, read only by finalize (no init needed)
constexpr int WQ  = 0;                    // qpart[BS][NSLICE][Q] d2 = 131072
constexpr int WC1 = WQ + BS * NSLICE * Q; // cd1 partial per phase-1 task [512]
constexpr int WB  = WC1 + NTASK1;         // bce partials [32]
constexpr int WCN = WB + 32;              // masked-cell-count partials [32]

// 256 blocks x 256 threads; each wave = one independent task, no block barriers.
__global__ __launch_bounds__(256) void chamfer_kernel(
        const float* __restrict__ pred,     // [BS,P,3]
        const float* __restrict__ probs,    // [BS,G]
        const float* __restrict__ gt,       // [BS,Q,3]
        const float* __restrict__ target,   // [BS,G]
        float* __restrict__ ws,
        float* __restrict__ out) {
    const int wid  = threadIdx.x >> 6;       // wave 0..3 (private LDS region)
    const int l    = threadIdx.x & 63;
    const int task = blockIdx.x * 4 + wid;   // 0..1023

    // per-wave staged SoA: [coord][group-of-4]; phase1 uses 64 groups, phase2 80
    __shared__ float4 sbuf[4][3][80];
    float4* sx4 = sbuf[wid][0];
    float4* sy4 = sbuf[wid][1];
    float4* sz4 = sbuf[wid][2];

    const int phase1 = (task < NTASK1);
    const int id = phase1 ? task : task - NTASK1;
    const int b  = id >> 5;                  // /NSLICE
    const int s  = id & (NSLICE - 1);

    if (task == 0 && l == 0) out[0] = 0.0f;  // replaces memset dispatch (pre-finalize)

    if (phase1) {
        // ---- cd1: stage 256 gt; own 5 pred points (strided l + 64j) ----
        const float4* gsrc = (const float4*)(gt + (size_t)b * Q * 3);
        float4 a0 = gsrc[3 * l], a1 = gsrc[3 * l + 1], a2 = gsrc[3 * l + 2];
        sx4[l] = make_float4(a0.x, a0.w, a1.z, a2.y);
        sy4[l] = make_float4(a0.y, a1.x, a1.w, a2.z);
        sz4[l] = make_float4(a0.z, a1.y, a2.x, a2.w);

        float oxr[5], oyr[5], ozr[5], om[5];
        const int p0 = s * SLICE + l;
        #pragma unroll
        for (int j = 0; j < 5; ++j) {
            const int p = p0 + 64 * j;
            const float* pp = pred + ((size_t)b * P + p) * 3;
            oxr[j] = pp[0]; oyr[j] = pp[1]; ozr[j] = pp[2];
            om[j] = (probs[b * G + p / S] > THRESHOLD) ? 1.0f : 0.0f;
        }

        float acc[5][4];
        #pragma unroll
        for (int j = 0; j < 5; ++j)
            #pragma unroll
            for (int k = 0; k < 4; ++k) acc[j][k] = FINF;

        #pragma unroll 4
        for (int g = 0; g < 64; ++g) {
            float4 X = sx4[g], Y = sy4[g], Z = sz4[g];   // uniform broadcast
            float gx[4] = {X.x, X.y, X.z, X.w};
            float gy[4] = {Y.x, Y.y, Y.z, Y.w};
            float gz[4] = {Z.x, Z.y, Z.z, Z.w};
            #pragma unroll
            for (int k = 0; k < 4; ++k)
                #pragma unroll
                for (int j = 0; j < 5; ++j) {
                    float dx = oxr[j] - gx[k];
                    float dy = oyr[j] - gy[k];
                    float dz = ozr[j] - gz[k];
                    float d  = dx * dx + dy * dy + dz * dz;
                    acc[j][k] = fminf(acc[j][k], d);
                }
        }
        float contrib = 0.0f;
        #pragma unroll
        for (int j = 0; j < 5; ++j) {
            float mn = fminf(fminf(acc[j][0], acc[j][1]), fminf(acc[j][2], acc[j][3]));
            contrib += om[j] * sqrtf(mn);
        }
        #pragma unroll
        for (int off = 32; off; off >>= 1) contrib += __shfl_down(contrib, off);
        if (l == 0) ws[WC1 + id] = contrib;

        // ---- BCE + mask-cell count folded into tasks 0..31 (256 cells each) ----
        if (task < 32) {
            float term = 0.0f, cells = 0.0f;
            #pragma unroll
            for (int j = 0; j < 4; ++j) {
                int cell = task * 256 + 4 * l + j;
                float pv = probs[cell];
                float tv = target[cell];
                term += -(tv * fmaxf(logf(pv), -100.0f) +
                          (1.0f - tv) * fmaxf(log1pf(-pv), -100.0f));
                cells += (pv > THRESHOLD) ? 1.0f : 0.0f;
            }
            #pragma unroll
            for (int off = 32; off; off >>= 1) {
                term  += __shfl_down(term, off);
                cells += __shfl_down(cells, off);
            }
            if (l == 0) { ws[WB + task] = term; ws[WCN + task] = cells; }
        }
    } else {
        // ---- cd2: stage 320 pred (mask-folded, strided scalar writes); own 4 gt ----
        float* sxf = (float*)sx4;
        float* syf = (float*)sy4;
        float* szf = (float*)sz4;
        const int p0 = s * SLICE + l;
        #pragma unroll
        for (int j = 0; j < 5; ++j) {
            const int p = p0 + 64 * j;
            const float* pp = pred + ((size_t)b * P + p) * 3;
            bool m = probs[b * G + p / S] > THRESHOLD;
            sxf[l + 64 * j] = m ? pp[0] : FARV;
            syf[l + 64 * j] = m ? pp[1] : FARV;
            szf[l + 64 * j] = m ? pp[2] : FARV;
        }

        const float4* gsrc = (const float4*)(gt + (size_t)b * Q * 3);
        float4 a0 = gsrc[3 * l], a1 = gsrc[3 * l + 1], a2 = gsrc[3 * l + 2];
        float ogx[4] = {a0.x, a0.w, a1.z, a2.y};   // x of gt points 4l..4l+3
        float ogy[4] = {a0.y, a1.x, a1.w, a2.z};
        float ogz[4] = {a0.z, a1.y, a2.x, a2.w};

        float acc[4][4];
        #pragma unroll
        for (int j = 0; j < 4; ++j)
            #pragma unroll
            for (int k = 0; k < 4; ++k) acc[j][k] = FINF;

        #pragma unroll 4
        for (int g = 0; g < 80; ++g) {
            float4 X = sx4[g], Y = sy4[g], Z = sz4[g];   // uniform broadcast
            float gx[4] = {X.x, X.y, X.z, X.w};
            float gy[4] = {Y.x, Y.y, Y.z, Y.w};
            float gz[4] = {Z.x, Z.y, Z.z, Z.w};
            #pragma unroll
            for (int k = 0; k < 4; ++k)
                #pragma unroll
                for (int j = 0; j < 4; ++j) {
                    float dx = ogx[j] - gx[k];
                    float dy = ogy[j] - gy[k];
                    float dz = ogz[j] - gz[k];
                    float d  = dx * dx + dy * dy + dz * dz;
                    acc[j][k] = fminf(acc[j][k], d);
                }
        }
        float4 v;
        v.x = fminf(fminf(acc[0][0], acc[0][1]), fminf(acc[0][2], acc[0][3]));
        v.y = fminf(fminf(acc[1][0], acc[1][1]), fminf(acc[1][2], acc[1][3]));
        v.z = fminf(fminf(acc[2][0], acc[2][1]), fminf(acc[2][2], acc[2][3]));
        v.w = fminf(fminf(acc[3][0], acc[3][1]), fminf(acc[3][2], acc[3][3]));
        // pure coalesced float4 store of this slice's per-gt min d2
        *(float4*)(ws + WQ + (size_t)id * Q + 4 * l) = v;
    }
}

// grid = 16 blocks x 256 threads; block b handles batch b.
// Thread q: min over 32 slice partials (coalesced, independent loads), sqrt, sum.
__global__ __launch_bounds__(256) void finalize_kernel(
        const float* __restrict__ ws, float* __restrict__ out) {
    const int b = blockIdx.x;
    const int t = threadIdx.x;              // == q
    __shared__ float sred[4];

    const float* qp = ws + WQ + (size_t)b * NSLICE * Q + t;
    float mnv = FINF;
    #pragma unroll
    for (int c = 0; c < NSLICE; ++c) mnv = fminf(mnv, qp[c * Q]);
    float s2 = sqrtf(mnv);

    // cd1 partials (threads 0..31) folded into the same reduction lanes
    float s1 = (t < NSLICE) ? ws[WC1 + b * NSLICE + t] : 0.0f;

    #pragma unroll
    for (int off = 32; off; off >>= 1) {
        s2 += __shfl_down(s2, off);
        s1 += __shfl_down(s1, off);
    }
    if ((t & 63) == 0) sred[t >> 6] = s2;   // s1 lives entirely in wave 0
    __syncthreads();

    if (t == 0) {
        float sum2 = sred[0] + sred[1] + sred[2] + sred[3];
        float cnt  = (ws[WCN + 2 * b] + ws[WCN + 2 * b + 1]) * (float)S;
        float cd1  = s1 / fmaxf(cnt, 1.0f);
        float cd2  = sum2 / (float)Q;
        float cdb  = (cnt > 0.0f) ? fmaxf(cd1, cd2) : 0.0f;
        atomicAdd(out, cdb / (float)BS);
    }
    // block 0, wave 1: BCE sum (32 partials)
    if (b == 0 && t >= 64 && t < 128) {
        int l = t - 64;
        float bb = (l < 32) ? ws[WB + l] : 0.0f;
        #pragma unroll
        for (int off = 32; off; off >>= 1) bb += __shfl_down(bb, off);
        if (l == 0) atomicAdd(out, bb / (float)(BS * G));
    }
}

extern "C" void kernel_launch(void* const* d_in, const int* in_sizes, int n_in,
                              void* d_out, int out_size, void* d_ws, size_t ws_size,
                              hipStream_t stream) {
    const float* diff_pred   = (const float*)d_in[0];
    const float* probs_pred  = (const float*)d_in[1];
    const float* diff_gt     = (const float*)d_in[2];
    const float* prob_target = (const float*)d_in[3];
    float* out = (float*)d_out;
    float* ws  = (float*)d_ws;

    chamfer_kernel<<<NTASKS / 4, 256, 0, stream>>>(
        diff_pred, probs_pred, diff_gt, prob_target, ws, out);
    finalize_kernel<<<BS, 256, 0, stream>>>(ws, out);
}